// Round 13
// baseline (282.023 us; speedup 1.0000x reference)
//
#include <hip/hip_runtime.h>
#include <hip/hip_bf16.h>
#include <stdint.h>

#define SEQ   2048
#define DM    4096
#define NH    32
#define NKV   8
#define HD    128
#define DKV   1024   // NKV*HD

typedef __attribute__((ext_vector_type(8))) short bf8_t;   // 8 bf16 (4 VGPR)
typedef __attribute__((ext_vector_type(4))) float f4_t;
typedef __attribute__((ext_vector_type(16))) float f16x;

__device__ __forceinline__ short f2bf(float f) {
  union { float f; uint32_t u; } v; v.f = f;
  uint32_t r = v.u + 0x7FFFu + ((v.u >> 16) & 1u);
  return (short)(r >> 16);
}
__device__ __forceinline__ float bf2f(short s) {
  union { uint32_t u; float f; } v; v.u = ((uint32_t)(uint16_t)s) << 16;
  return v.f;
}
__device__ __forceinline__ uint32_t cvtpk(float lo, float hi) {
  uint32_t r;
  asm("v_cvt_pk_bf16_f32 %0, %1, %2" : "=v"(r) : "v"(lo), "v"(hi));
  return r;
}

// CK-style global->LDS async copy, 16B per lane (lds addr must be lane-linear)
__device__ __forceinline__ void async_copy16(const void* gsrc, void* ldst) {
  auto g = reinterpret_cast<const __attribute__((address_space(1))) uint32_t*>(
      reinterpret_cast<uintptr_t>(gsrc));
  auto l = reinterpret_cast<__attribute__((address_space(3))) uint32_t*>(
      reinterpret_cast<uintptr_t>(ldst));
  __builtin_amdgcn_global_load_lds(g, l, 16, 0, 0);
}

__device__ __forceinline__ f4_t mfma16(bf8_t a, bf8_t b, f4_t c) {
  return __builtin_amdgcn_mfma_f32_16x16x32_bf16(a, b, c, 0, 0, 0);
}
__device__ __forceinline__ f16x mfma32(bf8_t a, bf8_t b, f16x c) {
  return __builtin_amdgcn_mfma_f32_32x32x16_bf16(a, b, c, 0, 0, 0);
}

template<int N> __device__ __forceinline__ void vmwait();
template<> __device__ __forceinline__ void vmwait<3>() {
  asm volatile("s_waitcnt vmcnt(3)" ::: "memory");
}
template<> __device__ __forceinline__ void vmwait<4>() {
  asm volatile("s_waitcnt vmcnt(4)" ::: "memory");
}

union U4B8 { uint32_t w[4]; bf8_t v; };

// ---------------- fused f32 -> bf16 convert (x, wq, wk, wv, wo) ----------------
// R8 showed f32-direct weight reads in the GEMMs lose 105us to exposed HBM
// latency; this ~45us conversion round-trip is the cheaper path (at HBM BW).
__global__ void cvt_all_kernel(const float* __restrict__ x,
                               const float* __restrict__ wq,
                               const float* __restrict__ wk,
                               const float* __restrict__ wv,
                               const float* __restrict__ wo,
                               short* __restrict__ out)
{
  const int E0 = SEQ * DM / 4;
  const int E1 = E0 + DM * DM / 4;
  const int E2 = E1 + DKV * DM / 4;
  const int E3 = E2 + DKV * DM / 4;
  const int E4 = E3 + DM * DM / 4;
  const int stride = gridDim.x * blockDim.x;
  for (int i = blockIdx.x * blockDim.x + threadIdx.x; i < E4; i += stride) {
    const float4* src; int off;
    if (i < E0)      { src = (const float4*)x;  off = i; }
    else if (i < E1) { src = (const float4*)wq; off = i - E0; }
    else if (i < E2) { src = (const float4*)wk; off = i - E1; }
    else if (i < E3) { src = (const float4*)wv; off = i - E2; }
    else             { src = (const float4*)wo; off = i - E3; }
    float4 v = src[off];
    short4 o;
    o.x = f2bf(v.x); o.y = f2bf(v.y); o.z = f2bf(v.z); o.w = f2bf(v.w);
    ((short4*)out)[i] = o;
  }
}

// ---------------- fat-phase GEMM: C = A[M][K] * B[N][K]^T (bf16), BK=64 ------
// 512 threads = 8 waves (2M x 4N). B staged in 64-row slabs (1 gload/wave).
// LDS [rows][64] bf16, 8x16B chunks/row, chunk-col ^= row&7 (T2, both sides).
// 2 fat phases per K-tile; vmcnt(SB) at ph1/ph3. Ledger (generic, verified
// for AJ=1 and AJ=2): prologue B0(SB)+A0(2*AJ)+B1(SB) -> vmcnt(SB) leaves B1.
// ph0 stages A1; ph1 stages B0(t+2), vmcnt(SB) drains B1+A1, leaves B0(t+2);
// symmetric ph2/ph3. WAR: each buffer's ds_reads drain at its phase's lgkm0
// before the barrier preceding its re-stage.
// R13: QKV moved to BM=128 (LDS 80KB -> 2 blocks/CU, 512 blocks): R12 proved
// QKV is traffic-insensitive (FETCH 2.3x, dur flat) -> the bound is barrier
// serialization at 1 block/CU; cross-block overlap (m114) is the lever.
// No XCD swizzle (R12: +3.6us, B-locality destroyed).
template<int MODE, int BM, int BN>
__global__ __launch_bounds__(512, 4)
void gemm8_kernel(const short* __restrict__ A,
                  const short* __restrict__ Bw,
                  float* __restrict__ Cf,
                  short* __restrict__ Cq,
                  short* __restrict__ Ck,
                  short* __restrict__ Cv)
{
  constexpr int MREP = BM / 32;     // 16x16 M-fragments per wave
  constexpr int SB   = BN / 64;     // B slabs (= N-fragments per wave)
  constexpr int SPP  = MREP / 2;    // M-slabs per fat phase
  constexpr int AJ   = BM / 128;    // stage issues per A-half per wave
  constexpr int NT   = DM / 64;     // K-tiles

  __shared__ short As[2][BM * 64];
  __shared__ short Bs[2][BN * 64];

  const int tid = threadIdx.x, lane = tid & 63, wid = tid >> 6;
  const int wr = wid >> 2, wn = wid & 3;
  const int cl = lane & 15, kh = lane >> 4;
  const int row0 = blockIdx.y * BM;
  const int col0 = blockIdx.x * BN;

  f4_t acc[MREP][SB];
  #pragma unroll
  for (int i = 0; i < MREP; i++)
    #pragma unroll
    for (int j = 0; j < SB; j++) { acc[i][j][0]=0.f; acc[i][j][1]=0.f; acc[i][j][2]=0.f; acc[i][j][3]=0.f; }

  auto STGA = [&](short* T, int h, int kt) {
    #pragma unroll
    for (int j = 0; j < AJ; ++j) {
      const int c = wid * (64 * AJ) + j * 64 + lane;   // [0, BM*4)
      const int row = h * (BM / 2) + (c >> 3), pcol = c & 7;
      const int lcol = pcol ^ (row & 7);
      async_copy16(&A[(size_t)(row0 + row) * DM + kt * 64 + lcol * 8],
                   &T[(h * (BM * 4) + c) * 8]);
    }
  };
  auto STGB = [&](short* T, int sl, int kt) {
    const int c = wid * 64 + lane;                     // [0, 512)
    const int row = sl * 64 + (c >> 3), pcol = c & 7;
    const int lcol = pcol ^ (row & 7);
    async_copy16(&Bw[(size_t)(col0 + row) * DM + kt * 64 + lcol * 8],
                 &T[(sl * 512 + c) * 8]);
  };

  bf8_t bF[SB][2];
  bf8_t aF[SPP][2];
  auto LDA = [&](const short* T, int ms0) {
    #pragma unroll
    for (int s = 0; s < SPP; ++s)
      #pragma unroll
      for (int q = 0; q < 2; ++q) {
        const int row = wr * (BM / 2) + (ms0 + s) * 16 + cl;
        const int pcol = (q * 4 + kh) ^ (row & 7);
        aF[s][q] = *(const bf8_t*)&T[(row * 8 + pcol) * 8];
      }
  };
  auto LDB = [&](const short* T) {
    #pragma unroll
    for (int n = 0; n < SB; ++n)
      #pragma unroll
      for (int q = 0; q < 2; ++q) {
        const int row = wn * (16 * SB) + n * 16 + cl;
        const int pcol = (q * 4 + kh) ^ (row & 7);
        bF[n][q] = *(const bf8_t*)&T[(row * 8 + pcol) * 8];
      }
  };

#define PHASE(TA, TB, PH, READB, STGSTMT, VMC)                                \
  {                                                                           \
    LDA(TA, (PH) * SPP);                                                      \
    if (READB) LDB(TB);                                                       \
    STGSTMT                                                                   \
    __builtin_amdgcn_s_barrier();                                             \
    asm volatile("s_waitcnt lgkmcnt(0)" ::: "memory");                        \
    __builtin_amdgcn_s_setprio(1);                                            \
    _Pragma("unroll")                                                         \
    for (int s_ = 0; s_ < SPP; ++s_) {                                        \
      _Pragma("unroll")                                                       \
      for (int n_ = 0; n_ < SB; ++n_) {                                       \
        _Pragma("unroll")                                                     \
        for (int q_ = 0; q_ < 2; ++q_)                                        \
          acc[(PH) * SPP + s_][n_] =                                          \
              mfma16(aF[s_][q_], bF[n_][q_], acc[(PH) * SPP + s_][n_]);       \
      }                                                                       \
    }                                                                         \
    __builtin_amdgcn_s_setprio(0);                                            \
    if (VMC) vmwait<SB>();                                                    \
    __builtin_amdgcn_s_barrier();                                             \
  }

  // prologue: B0 all slabs + A0 full + B1 all slabs; wait tile0 landed
  #pragma unroll
  for (int sl = 0; sl < SB; ++sl) STGB(Bs[0], sl, 0);
  STGA(As[0], 0, 0); STGA(As[0], 1, 0);
  #pragma unroll
  for (int sl = 0; sl < SB; ++sl) STGB(Bs[1], sl, 1);
  vmwait<SB>();
  __builtin_amdgcn_s_barrier();

  for (int i = 0; i < NT / 2; ++i) {
    const int t1 = 2 * i + 1;
    int t2 = 2 * i + 2; if (t2 > NT - 1) t2 = NT - 1;
    int t3 = 2 * i + 3; if (t3 > NT - 1) t3 = NT - 1;
    PHASE(As[0], Bs[0], 0, true,
          { STGA(As[1], 0, t1); STGA(As[1], 1, t1); }, false);
    PHASE(As[0], Bs[0], 1, false,
          { _Pragma("unroll") for (int sl = 0; sl < SB; ++sl) STGB(Bs[0], sl, t2); }, true);
    PHASE(As[1], Bs[1], 0, true,
          { STGA(As[0], 0, t2); STGA(As[0], 1, t2); }, false);
    PHASE(As[1], Bs[1], 1, false,
          { _Pragma("unroll") for (int sl = 0; sl < SB; ++sl) STGB(Bs[1], sl, t3); }, true);
  }
#undef PHASE

  // epilogue: C layout col = lane&15, row = (lane>>4)*4 + reg
  const int rb = kh * 4;
  #pragma unroll
  for (int mi = 0; mi < MREP; mi++) {
    const int m0 = row0 + wr * (BM / 2) + mi * 16 + rb;
    #pragma unroll
    for (int ni = 0; ni < SB; ni++) {
      const int n = col0 + wn * (16 * SB) + ni * 16 + cl;
      if (MODE == 0) {
        #pragma unroll
        for (int r = 0; r < 4; r++) Cf[(size_t)(m0 + r) * DM + n] = acc[mi][ni][r];
      } else if (n < DM) {
        #pragma unroll
        for (int r = 0; r < 4; r++) Cq[(size_t)(m0 + r) * DM + n] = f2bf(acc[mi][ni][r]);
      } else if (n < DM + DKV) {
        const int nk = n - DM;
        #pragma unroll
        for (int r = 0; r < 4; r++) Ck[(size_t)(m0 + r) * DKV + nk] = f2bf(acc[mi][ni][r]);
      } else {
        const int nv = n - DM - DKV;   // 0..1023 = kv_head*128 + d
        short4 pk;
        pk.x = f2bf(acc[mi][ni][0]); pk.y = f2bf(acc[mi][ni][1]);
        pk.z = f2bf(acc[mi][ni][2]); pk.w = f2bf(acc[mi][ni][3]);
        *(short4*)&Cv[(size_t)nv * SEQ + m0] = pk;
      }
    }
  }
}

// ---------------- RoPE in-place on K only (bf16), vectorized x4 pairs --------
__global__ void rope_k_kernel(short* __restrict__ Kb,
                              const float* __restrict__ fcos, const float* __restrict__ fsin)
{
  const int NKG = SEQ * (DKV / 8);   // 262144 groups of 4 pairs
  int idx = blockIdx.x * blockDim.x + threadIdx.x;
  if (idx >= NKG) return;
  const int s = idx >> 7, g = idx & 127;
  const int i0 = (g & 15) * 4;       // head-local pair index base
  const float4 cv = *(const float4*)&fcos[s * 64 + i0];
  const float4 sv = *(const float4*)&fsin[s * 64 + i0];
  short* ptr = Kb + (size_t)s * DKV + g * 8;
  U4B8 v = *(U4B8*)ptr;
  U4B8 o;
  {
    const float e0 = bf2f((short)(v.w[0] & 0xFFFF)), o0 = bf2f((short)(v.w[0] >> 16));
    o.w[0] = cvtpk(e0 * cv.x - o0 * sv.x, e0 * sv.x + o0 * cv.x);
    const float e1 = bf2f((short)(v.w[1] & 0xFFFF)), o1 = bf2f((short)(v.w[1] >> 16));
    o.w[1] = cvtpk(e1 * cv.y - o1 * sv.y, e1 * sv.y + o1 * cv.y);
    const float e2 = bf2f((short)(v.w[2] & 0xFFFF)), o2 = bf2f((short)(v.w[2] >> 16));
    o.w[2] = cvtpk(e2 * cv.z - o2 * sv.z, e2 * sv.z + o2 * cv.z);
    const float e3 = bf2f((short)(v.w[3] & 0xFFFF)), o3 = bf2f((short)(v.w[3] >> 16));
    o.w[3] = cvtpk(e3 * cv.w - o3 * sv.w, e3 * sv.w + o3 * cv.w);
  }
  *(U4B8*)ptr = o;
}

// ---------------- Flash attention (causal, GQA, 32x32 swapped MFMA) ----------
// R10 configuration, verbatim (measured best: setprio +4us, half-split +4.5us).
__device__ __forceinline__ void flash_stage(const short* __restrict__ Kb,
                                            const short* __restrict__ Vt,
                                            short* Kl, short* Vl,
                                            int kv0, int hkv, int wid, int lane)
{
  #pragma unroll
  for (int i = 0; i < 4; ++i) {                 // K: 64 rows x 16 chunks
    int c = wid * 256 + i * 64 + lane;
    int row = c >> 4, pos = c & 15;
    int dc = pos ^ (row & 7);                   // inverse-swizzled source chunk
    async_copy16(&Kb[(size_t)(kv0 + row) * DKV + hkv * HD + dc * 8], &Kl[c * 8]);
  }
  #pragma unroll
  for (int i = 0; i < 4; ++i) {                 // V^T: 128 rows x 8 chunks
    int c = wid * 256 + i * 64 + lane;
    int row = c >> 3, pos = c & 7;
    int kc = pos ^ (row & 7);
    async_copy16(&Vt[(size_t)(hkv * HD + row) * SEQ + kv0 + kc * 8], &Vl[c * 8]);
  }
}

__device__ __forceinline__ void flash_compute(const short* __restrict__ Kl,
                                              const short* __restrict__ Vl,
                                              const bf8_t* qF, f16x* accO,
                                              float& m_run, float& l_run,
                                              int kv0, int qw0, int c31, int hi)
{
  const float scale = 0.08838834764831845f;  // 1/sqrt(128)

  f16x accS[2];
  #pragma unroll
  for (int nu = 0; nu < 2; ++nu) {
    #pragma unroll
    for (int r = 0; r < 16; ++r) accS[nu][r] = 0.f;
  }
  #pragma unroll
  for (int nu = 0; nu < 2; ++nu) {
    const int row = nu * 32 + c31, rx = row & 7;
    #pragma unroll
    for (int s = 0; s < 8; ++s) {
      const int pos = (2 * s + hi) ^ rx;
      bf8_t kf = *(const bf8_t*)&Kl[row * 128 + pos * 8];
      accS[nu] = mfma32(kf, qF[s], accS[nu]);
    }
  }

  if (kv0 + 63 > qw0) {
    const int q_abs = qw0 + c31;
    #pragma unroll
    for (int nu = 0; nu < 2; ++nu)
      #pragma unroll
      for (int r = 0; r < 16; ++r) {
        const int kv_abs = kv0 + 32 * nu + (r & 3) + 8 * (r >> 2) + 4 * hi;
        if (kv_abs > q_abs) accS[nu][r] = -3.0e38f;
      }
  }

  float rm = -3.0e38f;
  #pragma unroll
  for (int nu = 0; nu < 2; ++nu)
    #pragma unroll
    for (int r = 0; r < 16; ++r) rm = fmaxf(rm, accS[nu][r]);
  rm = fmaxf(rm, __shfl_xor(rm, 32));
  const float pmax = rm * scale;
  if (!__all(pmax - m_run <= 8.0f)) {
    const float mnew = fmaxf(m_run, pmax);
    const float corr = __expf(m_run - mnew);
    m_run = mnew;
    l_run *= corr;
    #pragma unroll
    for (int dt = 0; dt < 4; ++dt)
      #pragma unroll
      for (int r = 0; r < 16; ++r) accO[dt][r] *= corr;
  }

  float tsum = 0.f;
  uint32_t u[8][2];
  #pragma unroll
  for (int m = 0; m < 8; ++m) {
    const int nu = m >> 2, rb = 4 * (m & 3);
    float p0 = __expf(fmaf(accS[nu][rb + 0], scale, -m_run));
    float p1 = __expf(fmaf(accS[nu][rb + 1], scale, -m_run));
    float p2 = __expf(fmaf(accS[nu][rb + 2], scale, -m_run));
    float p3 = __expf(fmaf(accS[nu][rb + 3], scale, -m_run));
    tsum += (p0 + p1) + (p2 + p3);
    u[m][0] = cvtpk(p0, p1);
    u[m][1] = cvtpk(p2, p3);
  }
  l_run += tsum + __shfl_xor(tsum, 32);

  bf8_t pa[4];
  #pragma unroll
  for (int ks = 0; ks < 4; ++ks) {
    const uint32_t a0 = u[2 * ks][0],     a1 = u[2 * ks][1];
    const uint32_t b0 = u[2 * ks + 1][0], b1 = u[2 * ks + 1][1];
    const uint32_t mp0 = hi ? a0 : b0, mp1 = hi ? a1 : b1;
    const uint32_t s0 = __shfl_xor(mp0, 32), s1 = __shfl_xor(mp1, 32);
    U4B8 f;
    f.w[0] = hi ? s0 : a0;
    f.w[1] = hi ? s1 : a1;
    f.w[2] = hi ? b0 : s0;
    f.w[3] = hi ? b1 : s1;
    pa[ks] = f.v;
  }

  #pragma unroll
  for (int dt = 0; dt < 4; ++dt) {
    const int row = dt * 32 + c31, rx = row & 7;
    #pragma unroll
    for (int ks = 0; ks < 4; ++ks) {
      const int pos = (2 * ks + hi) ^ rx;
      bf8_t vf = *(const bf8_t*)&Vl[row * 64 + pos * 8];
      accO[dt] = mfma32(vf, pa[ks], accO[dt]);
    }
  }
}

__global__ __launch_bounds__(256, 2)
void flash_kernel(const short* __restrict__ Qb,   // [SEQ][DM], UNroped
                  const short* __restrict__ Kb,   // [SEQ][DKV], roped
                  const short* __restrict__ Vt,   // [DKV][SEQ] transposed
                  const float* __restrict__ fcos,
                  const float* __restrict__ fsin,
                  short* __restrict__ Ob)
{
  __shared__ short Kl0[64 * 128], Kl1[64 * 128];
  __shared__ short Vl0[128 * 64], Vl1[128 * 64];

  const int tid = threadIdx.x, lane = tid & 63, wid = tid >> 6;
  const int c31 = lane & 31, hi = lane >> 5;

  const int b = blockIdx.x;
  const int pairid = b & 255, halfsel = b >> 8;
  const int h = pairid >> 3, p = pairid & 7;
  const int qt = halfsel ? (15 - p) : p;
  const int q0 = qt * 128;
  const int hkv = h >> 2;
  const int qw0 = q0 + wid * 32;

  // Q B-fragments with fused RoPE (pair partner adjacent in the 16B group).
  bf8_t qF[8];
  {
    const int qrow = qw0 + c31;
    const size_t qb = (size_t)qrow * DM + h * HD + hi * 8;
    const int tb = qrow * 64 + hi * 4;
    #pragma unroll
    for (int s = 0; s < 8; ++s) {
      U4B8 v; v.v = *(const bf8_t*)&Qb[qb + s * 16];
      const float4 cv = *(const float4*)&fcos[tb + s * 8];
      const float4 sv = *(const float4*)&fsin[tb + s * 8];
      U4B8 o;
      {
        const float e0 = bf2f((short)(v.w[0] & 0xFFFF)), d0 = bf2f((short)(v.w[0] >> 16));
        o.w[0] = cvtpk(e0 * cv.x - d0 * sv.x, e0 * sv.x + d0 * cv.x);
        const float e1 = bf2f((short)(v.w[1] & 0xFFFF)), d1 = bf2f((short)(v.w[1] >> 16));
        o.w[1] = cvtpk(e1 * cv.y - d1 * sv.y, e1 * sv.y + d1 * cv.y);
        const float e2 = bf2f((short)(v.w[2] & 0xFFFF)), d2 = bf2f((short)(v.w[2] >> 16));
        o.w[2] = cvtpk(e2 * cv.z - d2 * sv.z, e2 * sv.z + d2 * cv.z);
        const float e3 = bf2f((short)(v.w[3] & 0xFFFF)), d3 = bf2f((short)(v.w[3] >> 16));
        o.w[3] = cvtpk(e3 * cv.w - d3 * sv.w, e3 * sv.w + d3 * cv.w);
      }
      qF[s] = o.v;
    }
  }

  f16x accO[4];
  #pragma unroll
  for (int dt = 0; dt < 4; ++dt)
    #pragma unroll
    for (int r = 0; r < 16; ++r) accO[dt][r] = 0.f;
  float m_run = -INFINITY, l_run = 0.f;

  const int nt = (q0 >> 6) + 2;

  flash_stage(Kb, Vt, Kl0, Vl0, 0, hkv, wid, lane);
  __syncthreads();
  for (int t = 0; t < nt; t += 2) {
    flash_stage(Kb, Vt, Kl1, Vl1, (t + 1) * 64, hkv, wid, lane);
    if (t * 64 <= qw0 + 31)
      flash_compute(Kl0, Vl0, qF, accO, m_run, l_run, t * 64, qw0, c31, hi);
    __syncthreads();
    if (t + 2 < nt) flash_stage(Kb, Vt, Kl0, Vl0, (t + 2) * 64, hkv, wid, lane);
    if ((t + 1) * 64 <= qw0 + 31)
      flash_compute(Kl1, Vl1, qF, accO, m_run, l_run, (t + 1) * 64, qw0, c31, hi);
    __syncthreads();
  }

  short* Ol = (wid < 2) ? &Kl0[wid * 4096] : &Kl1[(wid - 2) * 4096];
  const float oinv = 1.0f / l_run;
  #pragma unroll
  for (int dt = 0; dt < 4; ++dt)
    #pragma unroll
    for (int w = 0; w < 8; ++w) {
      const int r = 2 * w;
      const int d0 = (r & 3) + 8 * (r >> 2) + 4 * hi + dt * 32;
      const uint32_t pk = cvtpk(accO[dt][r] * oinv, accO[dt][r + 1] * oinv);
      const int pos = (d0 >> 3) ^ (c31 & 7);
      *(uint32_t*)&Ol[c31 * 128 + pos * 8 + (d0 & 7)] = pk;
    }
  __syncthreads();
  const int rowq = lane >> 1;
  #pragma unroll
  for (int i = 0; i < 8; ++i) {
    const int dc = (lane & 1) * 8 + i;
    const int pos = dc ^ (rowq & 7);
    int4 v = *(const int4*)&Ol[rowq * 128 + pos * 8];
    *(int4*)&Ob[(size_t)(q0 + wid * 32 + rowq) * DM + h * HD + dc * 8] = v;
  }
}

// ---------------- launch ----------------
extern "C" void kernel_launch(void* const* d_in, const int* in_sizes, int n_in,
                              void* d_out, int out_size, void* d_ws, size_t ws_size,
                              hipStream_t stream)
{
  const float* x    = (const float*)d_in[0];
  const float* fcos = (const float*)d_in[1];
  const float* fsin = (const float*)d_in[2];
  const float* wq   = (const float*)d_in[3];
  const float* wk   = (const float*)d_in[4];
  const float* wv   = (const float*)d_in[5];
  const float* wo   = (const float*)d_in[6];
  float* out = (float*)d_out;

  char* p = (char*)d_ws;
  short* xb  = (short*)p; p += (size_t)SEQ * DM * 2;
  short* wqb = (short*)p; p += (size_t)DM * DM * 2;    // wqb..wvb contiguous = W[6144][4096]
  short* wkb = (short*)p; p += (size_t)DKV * DM * 2;
  short* wvb = (short*)p; p += (size_t)DKV * DM * 2;
  short* wob = (short*)p; p += (size_t)DM * DM * 2;
  short* Qb  = (short*)p; p += (size_t)SEQ * DM * 2;
  short* Kb  = (short*)p; p += (size_t)SEQ * DKV * 2;
  short* Vt  = (short*)p; p += (size_t)DKV * SEQ * 2;
  short* Ab  = (short*)p; p += (size_t)SEQ * DM * 2;
  (void)wkb; (void)wvb;

  cvt_all_kernel<<<2048, 256, 0, stream>>>(x, wq, wk, wv, wo, xb);

  gemm8_kernel<1, 128, 192><<<dim3(32, 16), 512, 0, stream>>>(xb, wqb,
                                                              nullptr, Qb, Kb, Vt);
  rope_k_kernel<<<1024, 256, 0, stream>>>(Kb, fcos, fsin);
  flash_kernel<<<512, 256, 0, stream>>>(Qb, Kb, Vt, fcos, fsin, Ab);
  gemm8_kernel<0, 128, 256><<<dim3(16, 16), 512, 0, stream>>>(Ab, wob,
                                                              out, nullptr, nullptr, nullptr);
}

// Round 14
// 275.650 us; speedup vs baseline: 1.0231x; 1.0231x over previous
//
#include <hip/hip_runtime.h>
#include <hip/hip_bf16.h>
#include <stdint.h>

#define SEQ   2048
#define DM    4096
#define NH    32
#define NKV   8
#define HD    128
#define DKV   1024   // NKV*HD

typedef __attribute__((ext_vector_type(8))) short bf8_t;   // 8 bf16 (4 VGPR)
typedef __attribute__((ext_vector_type(4))) float f4_t;
typedef __attribute__((ext_vector_type(16))) float f16x;

__device__ __forceinline__ short f2bf(float f) {
  union { float f; uint32_t u; } v; v.f = f;
  uint32_t r = v.u + 0x7FFFu + ((v.u >> 16) & 1u);
  return (short)(r >> 16);
}
__device__ __forceinline__ float bf2f(short s) {
  union { uint32_t u; float f; } v; v.u = ((uint32_t)(uint16_t)s) << 16;
  return v.f;
}
__device__ __forceinline__ uint32_t cvtpk(float lo, float hi) {
  uint32_t r;
  asm("v_cvt_pk_bf16_f32 %0, %1, %2" : "=v"(r) : "v"(lo), "v"(hi));
  return r;
}

// CK-style global->LDS async copy, 16B per lane (lds addr must be lane-linear)
__device__ __forceinline__ void async_copy16(const void* gsrc, void* ldst) {
  auto g = reinterpret_cast<const __attribute__((address_space(1))) uint32_t*>(
      reinterpret_cast<uintptr_t>(gsrc));
  auto l = reinterpret_cast<__attribute__((address_space(3))) uint32_t*>(
      reinterpret_cast<uintptr_t>(ldst));
  __builtin_amdgcn_global_load_lds(g, l, 16, 0, 0);
}

__device__ __forceinline__ f4_t mfma16(bf8_t a, bf8_t b, f4_t c) {
  return __builtin_amdgcn_mfma_f32_16x16x32_bf16(a, b, c, 0, 0, 0);
}
__device__ __forceinline__ f16x mfma32(bf8_t a, bf8_t b, f16x c) {
  return __builtin_amdgcn_mfma_f32_32x32x16_bf16(a, b, c, 0, 0, 0);
}

template<int N> __device__ __forceinline__ void vmwait();
template<> __device__ __forceinline__ void vmwait<3>() {
  asm volatile("s_waitcnt vmcnt(3)" ::: "memory");
}
template<> __device__ __forceinline__ void vmwait<4>() {
  asm volatile("s_waitcnt vmcnt(4)" ::: "memory");
}

union U4B8 { uint32_t w[4]; bf8_t v; };

// ---------------- fused f32 -> bf16 convert (x, wq, wk, wv, wo) ----------------
// R8 showed f32-direct weight reads in the GEMMs lose 105us to exposed HBM
// latency; this ~45us conversion round-trip is the cheaper path (at HBM BW).
__global__ void cvt_all_kernel(const float* __restrict__ x,
                               const float* __restrict__ wq,
                               const float* __restrict__ wk,
                               const float* __restrict__ wv,
                               const float* __restrict__ wo,
                               short* __restrict__ out)
{
  const int E0 = SEQ * DM / 4;
  const int E1 = E0 + DM * DM / 4;
  const int E2 = E1 + DKV * DM / 4;
  const int E3 = E2 + DKV * DM / 4;
  const int E4 = E3 + DM * DM / 4;
  const int stride = gridDim.x * blockDim.x;
  for (int i = blockIdx.x * blockDim.x + threadIdx.x; i < E4; i += stride) {
    const float4* src; int off;
    if (i < E0)      { src = (const float4*)x;  off = i; }
    else if (i < E1) { src = (const float4*)wq; off = i - E0; }
    else if (i < E2) { src = (const float4*)wk; off = i - E1; }
    else if (i < E3) { src = (const float4*)wv; off = i - E2; }
    else             { src = (const float4*)wo; off = i - E3; }
    float4 v = src[off];
    short4 o;
    o.x = f2bf(v.x); o.y = f2bf(v.y); o.z = f2bf(v.z); o.w = f2bf(v.w);
    ((short4*)out)[i] = o;
  }
}

// ---------------- fat-phase GEMM: C = A[M][K] * B[N][K]^T (bf16), BK=64 ------
// 512 threads = 8 waves (2M x 4N). B staged in 64-row slabs (1 gload/wave).
// LDS [rows][64] bf16, 8x16B chunks/row, chunk-col ^= row&7 (T2, both sides).
// 2 fat phases per K-tile; vmcnt(SB) at ph1/ph3 (ledger verified, R9 notes).
// MEASURED-BEST CONFIG (R9/R10, 275.9us total): QKV BM=256 grid(32,8)
// 1 block/CU; WO BM=128 grid(16,16). Falsified alternatives: XCD swizzle
// (R12 +3.6us, FETCH 2.3x), BM=128 QKV 2 blocks/CU (R13 +4.1us), f32-direct
// B (R8 +67us), rope-in-epilogue (R6 +24us). QKV is structure-bound at
// MfmaUtil ~45% across all variants. FROZEN.
template<int MODE, int BM, int BN>
__global__ __launch_bounds__(512, 2)
void gemm8_kernel(const short* __restrict__ A,
                  const short* __restrict__ Bw,
                  float* __restrict__ Cf,
                  short* __restrict__ Cq,
                  short* __restrict__ Ck,
                  short* __restrict__ Cv)
{
  constexpr int MREP = BM / 32;     // 16x16 M-fragments per wave
  constexpr int SB   = BN / 64;     // B slabs (= N-fragments per wave)
  constexpr int SPP  = MREP / 2;    // M-slabs per fat phase
  constexpr int AJ   = BM / 128;    // stage issues per A-half per wave
  constexpr int NT   = DM / 64;     // K-tiles

  __shared__ short As[2][BM * 64];
  __shared__ short Bs[2][BN * 64];

  const int tid = threadIdx.x, lane = tid & 63, wid = tid >> 6;
  const int wr = wid >> 2, wn = wid & 3;
  const int cl = lane & 15, kh = lane >> 4;
  const int row0 = blockIdx.y * BM;
  const int col0 = blockIdx.x * BN;

  f4_t acc[MREP][SB];
  #pragma unroll
  for (int i = 0; i < MREP; i++)
    #pragma unroll
    for (int j = 0; j < SB; j++) { acc[i][j][0]=0.f; acc[i][j][1]=0.f; acc[i][j][2]=0.f; acc[i][j][3]=0.f; }

  auto STGA = [&](short* T, int h, int kt) {
    #pragma unroll
    for (int j = 0; j < AJ; ++j) {
      const int c = wid * (64 * AJ) + j * 64 + lane;   // [0, BM*4)
      const int row = h * (BM / 2) + (c >> 3), pcol = c & 7;
      const int lcol = pcol ^ (row & 7);
      async_copy16(&A[(size_t)(row0 + row) * DM + kt * 64 + lcol * 8],
                   &T[(h * (BM * 4) + c) * 8]);
    }
  };
  auto STGB = [&](short* T, int sl, int kt) {
    const int c = wid * 64 + lane;                     // [0, 512)
    const int row = sl * 64 + (c >> 3), pcol = c & 7;
    const int lcol = pcol ^ (row & 7);
    async_copy16(&Bw[(size_t)(col0 + row) * DM + kt * 64 + lcol * 8],
                 &T[(sl * 512 + c) * 8]);
  };

  bf8_t bF[SB][2];
  bf8_t aF[SPP][2];
  auto LDA = [&](const short* T, int ms0) {
    #pragma unroll
    for (int s = 0; s < SPP; ++s)
      #pragma unroll
      for (int q = 0; q < 2; ++q) {
        const int row = wr * (BM / 2) + (ms0 + s) * 16 + cl;
        const int pcol = (q * 4 + kh) ^ (row & 7);
        aF[s][q] = *(const bf8_t*)&T[(row * 8 + pcol) * 8];
      }
  };
  auto LDB = [&](const short* T) {
    #pragma unroll
    for (int n = 0; n < SB; ++n)
      #pragma unroll
      for (int q = 0; q < 2; ++q) {
        const int row = wn * (16 * SB) + n * 16 + cl;
        const int pcol = (q * 4 + kh) ^ (row & 7);
        bF[n][q] = *(const bf8_t*)&T[(row * 8 + pcol) * 8];
      }
  };

#define PHASE(TA, TB, PH, READB, STGSTMT, VMC)                                \
  {                                                                           \
    LDA(TA, (PH) * SPP);                                                      \
    if (READB) LDB(TB);                                                       \
    STGSTMT                                                                   \
    __builtin_amdgcn_s_barrier();                                             \
    asm volatile("s_waitcnt lgkmcnt(0)" ::: "memory");                        \
    __builtin_amdgcn_s_setprio(1);                                            \
    _Pragma("unroll")                                                         \
    for (int s_ = 0; s_ < SPP; ++s_) {                                        \
      _Pragma("unroll")                                                       \
      for (int n_ = 0; n_ < SB; ++n_) {                                       \
        _Pragma("unroll")                                                     \
        for (int q_ = 0; q_ < 2; ++q_)                                        \
          acc[(PH) * SPP + s_][n_] =                                          \
              mfma16(aF[s_][q_], bF[n_][q_], acc[(PH) * SPP + s_][n_]);       \
      }                                                                       \
    }                                                                         \
    __builtin_amdgcn_s_setprio(0);                                            \
    if (VMC) vmwait<SB>();                                                    \
    __builtin_amdgcn_s_barrier();                                             \
  }

  // prologue: B0 all slabs + A0 full + B1 all slabs; wait tile0 landed
  #pragma unroll
  for (int sl = 0; sl < SB; ++sl) STGB(Bs[0], sl, 0);
  STGA(As[0], 0, 0); STGA(As[0], 1, 0);
  #pragma unroll
  for (int sl = 0; sl < SB; ++sl) STGB(Bs[1], sl, 1);
  vmwait<SB>();
  __builtin_amdgcn_s_barrier();

  for (int i = 0; i < NT / 2; ++i) {
    const int t1 = 2 * i + 1;
    int t2 = 2 * i + 2; if (t2 > NT - 1) t2 = NT - 1;
    int t3 = 2 * i + 3; if (t3 > NT - 1) t3 = NT - 1;
    PHASE(As[0], Bs[0], 0, true,
          { STGA(As[1], 0, t1); STGA(As[1], 1, t1); }, false);
    PHASE(As[0], Bs[0], 1, false,
          { _Pragma("unroll") for (int sl = 0; sl < SB; ++sl) STGB(Bs[0], sl, t2); }, true);
    PHASE(As[1], Bs[1], 0, true,
          { STGA(As[0], 0, t2); STGA(As[0], 1, t2); }, false);
    PHASE(As[1], Bs[1], 1, false,
          { _Pragma("unroll") for (int sl = 0; sl < SB; ++sl) STGB(Bs[1], sl, t3); }, true);
  }
#undef PHASE

  // epilogue: C layout col = lane&15, row = (lane>>4)*4 + reg
  const int rb = kh * 4;
  #pragma unroll
  for (int mi = 0; mi < MREP; mi++) {
    const int m0 = row0 + wr * (BM / 2) + mi * 16 + rb;
    #pragma unroll
    for (int ni = 0; ni < SB; ni++) {
      const int n = col0 + wn * (16 * SB) + ni * 16 + cl;
      if (MODE == 0) {
        #pragma unroll
        for (int r = 0; r < 4; r++) Cf[(size_t)(m0 + r) * DM + n] = acc[mi][ni][r];
      } else if (n < DM) {
        #pragma unroll
        for (int r = 0; r < 4; r++) Cq[(size_t)(m0 + r) * DM + n] = f2bf(acc[mi][ni][r]);
      } else if (n < DM + DKV) {
        const int nk = n - DM;
        #pragma unroll
        for (int r = 0; r < 4; r++) Ck[(size_t)(m0 + r) * DKV + nk] = f2bf(acc[mi][ni][r]);
      } else {
        const int nv = n - DM - DKV;   // 0..1023 = kv_head*128 + d
        short4 pk;
        pk.x = f2bf(acc[mi][ni][0]); pk.y = f2bf(acc[mi][ni][1]);
        pk.z = f2bf(acc[mi][ni][2]); pk.w = f2bf(acc[mi][ni][3]);
        *(short4*)&Cv[(size_t)nv * SEQ + m0] = pk;
      }
    }
  }
}

// ---------------- RoPE in-place on K only (bf16), vectorized x4 pairs --------
__global__ void rope_k_kernel(short* __restrict__ Kb,
                              const float* __restrict__ fcos, const float* __restrict__ fsin)
{
  const int NKG = SEQ * (DKV / 8);   // 262144 groups of 4 pairs
  int idx = blockIdx.x * blockDim.x + threadIdx.x;
  if (idx >= NKG) return;
  const int s = idx >> 7, g = idx & 127;
  const int i0 = (g & 15) * 4;       // head-local pair index base
  const float4 cv = *(const float4*)&fcos[s * 64 + i0];
  const float4 sv = *(const float4*)&fsin[s * 64 + i0];
  short* ptr = Kb + (size_t)s * DKV + g * 8;
  U4B8 v = *(U4B8*)ptr;
  U4B8 o;
  {
    const float e0 = bf2f((short)(v.w[0] & 0xFFFF)), o0 = bf2f((short)(v.w[0] >> 16));
    o.w[0] = cvtpk(e0 * cv.x - o0 * sv.x, e0 * sv.x + o0 * cv.x);
    const float e1 = bf2f((short)(v.w[1] & 0xFFFF)), o1 = bf2f((short)(v.w[1] >> 16));
    o.w[1] = cvtpk(e1 * cv.y - o1 * sv.y, e1 * sv.y + o1 * cv.y);
    const float e2 = bf2f((short)(v.w[2] & 0xFFFF)), o2 = bf2f((short)(v.w[2] >> 16));
    o.w[2] = cvtpk(e2 * cv.z - o2 * sv.z, e2 * sv.z + o2 * cv.z);
    const float e3 = bf2f((short)(v.w[3] & 0xFFFF)), o3 = bf2f((short)(v.w[3] >> 16));
    o.w[3] = cvtpk(e3 * cv.w - o3 * sv.w, e3 * sv.w + o3 * cv.w);
  }
  *(U4B8*)ptr = o;
}

// ---------------- Flash attention (causal, GQA, 32x32 swapped MFMA) ----------
// R10 configuration, verbatim (measured best: setprio +4us, half-split +4.5us).
__device__ __forceinline__ void flash_stage(const short* __restrict__ Kb,
                                            const short* __restrict__ Vt,
                                            short* Kl, short* Vl,
                                            int kv0, int hkv, int wid, int lane)
{
  #pragma unroll
  for (int i = 0; i < 4; ++i) {                 // K: 64 rows x 16 chunks
    int c = wid * 256 + i * 64 + lane;
    int row = c >> 4, pos = c & 15;
    int dc = pos ^ (row & 7);                   // inverse-swizzled source chunk
    async_copy16(&Kb[(size_t)(kv0 + row) * DKV + hkv * HD + dc * 8], &Kl[c * 8]);
  }
  #pragma unroll
  for (int i = 0; i < 4; ++i) {                 // V^T: 128 rows x 8 chunks
    int c = wid * 256 + i * 64 + lane;
    int row = c >> 3, pos = c & 7;
    int kc = pos ^ (row & 7);
    async_copy16(&Vt[(size_t)(hkv * HD + row) * SEQ + kv0 + kc * 8], &Vl[c * 8]);
  }
}

__device__ __forceinline__ void flash_compute(const short* __restrict__ Kl,
                                              const short* __restrict__ Vl,
                                              const bf8_t* qF, f16x* accO,
                                              float& m_run, float& l_run,
                                              int kv0, int qw0, int c31, int hi)
{
  const float scale = 0.08838834764831845f;  // 1/sqrt(128)

  f16x accS[2];
  #pragma unroll
  for (int nu = 0; nu < 2; ++nu) {
    #pragma unroll
    for (int r = 0; r < 16; ++r) accS[nu][r] = 0.f;
  }
  #pragma unroll
  for (int nu = 0; nu < 2; ++nu) {
    const int row = nu * 32 + c31, rx = row & 7;
    #pragma unroll
    for (int s = 0; s < 8; ++s) {
      const int pos = (2 * s + hi) ^ rx;
      bf8_t kf = *(const bf8_t*)&Kl[row * 128 + pos * 8];
      accS[nu] = mfma32(kf, qF[s], accS[nu]);
    }
  }

  if (kv0 + 63 > qw0) {
    const int q_abs = qw0 + c31;
    #pragma unroll
    for (int nu = 0; nu < 2; ++nu)
      #pragma unroll
      for (int r = 0; r < 16; ++r) {
        const int kv_abs = kv0 + 32 * nu + (r & 3) + 8 * (r >> 2) + 4 * hi;
        if (kv_abs > q_abs) accS[nu][r] = -3.0e38f;
      }
  }

  float rm = -3.0e38f;
  #pragma unroll
  for (int nu = 0; nu < 2; ++nu)
    #pragma unroll
    for (int r = 0; r < 16; ++r) rm = fmaxf(rm, accS[nu][r]);
  rm = fmaxf(rm, __shfl_xor(rm, 32));
  const float pmax = rm * scale;
  if (!__all(pmax - m_run <= 8.0f)) {
    const float mnew = fmaxf(m_run, pmax);
    const float corr = __expf(m_run - mnew);
    m_run = mnew;
    l_run *= corr;
    #pragma unroll
    for (int dt = 0; dt < 4; ++dt)
      #pragma unroll
      for (int r = 0; r < 16; ++r) accO[dt][r] *= corr;
  }

  float tsum = 0.f;
  uint32_t u[8][2];
  #pragma unroll
  for (int m = 0; m < 8; ++m) {
    const int nu = m >> 2, rb = 4 * (m & 3);
    float p0 = __expf(fmaf(accS[nu][rb + 0], scale, -m_run));
    float p1 = __expf(fmaf(accS[nu][rb + 1], scale, -m_run));
    float p2 = __expf(fmaf(accS[nu][rb + 2], scale, -m_run));
    float p3 = __expf(fmaf(accS[nu][rb + 3], scale, -m_run));
    tsum += (p0 + p1) + (p2 + p3);
    u[m][0] = cvtpk(p0, p1);
    u[m][1] = cvtpk(p2, p3);
  }
  l_run += tsum + __shfl_xor(tsum, 32);

  bf8_t pa[4];
  #pragma unroll
  for (int ks = 0; ks < 4; ++ks) {
    const uint32_t a0 = u[2 * ks][0],     a1 = u[2 * ks][1];
    const uint32_t b0 = u[2 * ks + 1][0], b1 = u[2 * ks + 1][1];
    const uint32_t mp0 = hi ? a0 : b0, mp1 = hi ? a1 : b1;
    const uint32_t s0 = __shfl_xor(mp0, 32), s1 = __shfl_xor(mp1, 32);
    U4B8 f;
    f.w[0] = hi ? s0 : a0;
    f.w[1] = hi ? s1 : a1;
    f.w[2] = hi ? b0 : s0;
    f.w[3] = hi ? b1 : s1;
    pa[ks] = f.v;
  }

  #pragma unroll
  for (int dt = 0; dt < 4; ++dt) {
    const int row = dt * 32 + c31, rx = row & 7;
    #pragma unroll
    for (int ks = 0; ks < 4; ++ks) {
      const int pos = (2 * ks + hi) ^ rx;
      bf8_t vf = *(const bf8_t*)&Vl[row * 64 + pos * 8];
      accO[dt] = mfma32(vf, pa[ks], accO[dt]);
    }
  }
}

__global__ __launch_bounds__(256, 2)
void flash_kernel(const short* __restrict__ Qb,   // [SEQ][DM], UNroped
                  const short* __restrict__ Kb,   // [SEQ][DKV], roped
                  const short* __restrict__ Vt,   // [DKV][SEQ] transposed
                  const float* __restrict__ fcos,
                  const float* __restrict__ fsin,
                  short* __restrict__ Ob)
{
  __shared__ short Kl0[64 * 128], Kl1[64 * 128];
  __shared__ short Vl0[128 * 64], Vl1[128 * 64];

  const int tid = threadIdx.x, lane = tid & 63, wid = tid >> 6;
  const int c31 = lane & 31, hi = lane >> 5;

  const int b = blockIdx.x;
  const int pairid = b & 255, halfsel = b >> 8;
  const int h = pairid >> 3, p = pairid & 7;
  const int qt = halfsel ? (15 - p) : p;
  const int q0 = qt * 128;
  const int hkv = h >> 2;
  const int qw0 = q0 + wid * 32;

  // Q B-fragments with fused RoPE (pair partner adjacent in the 16B group).
  bf8_t qF[8];
  {
    const int qrow = qw0 + c31;
    const size_t qb = (size_t)qrow * DM + h * HD + hi * 8;
    const int tb = qrow * 64 + hi * 4;
    #pragma unroll
    for (int s = 0; s < 8; ++s) {
      U4B8 v; v.v = *(const bf8_t*)&Qb[qb + s * 16];
      const float4 cv = *(const float4*)&fcos[tb + s * 8];
      const float4 sv = *(const float4*)&fsin[tb + s * 8];
      U4B8 o;
      {
        const float e0 = bf2f((short)(v.w[0] & 0xFFFF)), d0 = bf2f((short)(v.w[0] >> 16));
        o.w[0] = cvtpk(e0 * cv.x - d0 * sv.x, e0 * sv.x + d0 * cv.x);
        const float e1 = bf2f((short)(v.w[1] & 0xFFFF)), d1 = bf2f((short)(v.w[1] >> 16));
        o.w[1] = cvtpk(e1 * cv.y - d1 * sv.y, e1 * sv.y + d1 * cv.y);
        const float e2 = bf2f((short)(v.w[2] & 0xFFFF)), d2 = bf2f((short)(v.w[2] >> 16));
        o.w[2] = cvtpk(e2 * cv.z - d2 * sv.z, e2 * sv.z + d2 * cv.z);
        const float e3 = bf2f((short)(v.w[3] & 0xFFFF)), d3 = bf2f((short)(v.w[3] >> 16));
        o.w[3] = cvtpk(e3 * cv.w - d3 * sv.w, e3 * sv.w + d3 * cv.w);
      }
      qF[s] = o.v;
    }
  }

  f16x accO[4];
  #pragma unroll
  for (int dt = 0; dt < 4; ++dt)
    #pragma unroll
    for (int r = 0; r < 16; ++r) accO[dt][r] = 0.f;
  float m_run = -INFINITY, l_run = 0.f;

  const int nt = (q0 >> 6) + 2;

  flash_stage(Kb, Vt, Kl0, Vl0, 0, hkv, wid, lane);
  __syncthreads();
  for (int t = 0; t < nt; t += 2) {
    flash_stage(Kb, Vt, Kl1, Vl1, (t + 1) * 64, hkv, wid, lane);
    if (t * 64 <= qw0 + 31)
      flash_compute(Kl0, Vl0, qF, accO, m_run, l_run, t * 64, qw0, c31, hi);
    __syncthreads();
    if (t + 2 < nt) flash_stage(Kb, Vt, Kl0, Vl0, (t + 2) * 64, hkv, wid, lane);
    if ((t + 1) * 64 <= qw0 + 31)
      flash_compute(Kl1, Vl1, qF, accO, m_run, l_run, (t + 1) * 64, qw0, c31, hi);
    __syncthreads();
  }

  short* Ol = (wid < 2) ? &Kl0[wid * 4096] : &Kl1[(wid - 2) * 4096];
  const float oinv = 1.0f / l_run;
  #pragma unroll
  for (int dt = 0; dt < 4; ++dt)
    #pragma unroll
    for (int w = 0; w < 8; ++w) {
      const int r = 2 * w;
      const int d0 = (r & 3) + 8 * (r >> 2) + 4 * hi + dt * 32;
      const uint32_t pk = cvtpk(accO[dt][r] * oinv, accO[dt][r + 1] * oinv);
      const int pos = (d0 >> 3) ^ (c31 & 7);
      *(uint32_t*)&Ol[c31 * 128 + pos * 8 + (d0 & 7)] = pk;
    }
  __syncthreads();
  const int rowq = lane >> 1;
  #pragma unroll
  for (int i = 0; i < 8; ++i) {
    const int dc = (lane & 1) * 8 + i;
    const int pos = dc ^ (rowq & 7);
    int4 v = *(const int4*)&Ol[rowq * 128 + pos * 8];
    *(int4*)&Ob[(size_t)(q0 + wid * 32 + rowq) * DM + h * HD + dc * 8] = v;
  }
}

// ---------------- launch ----------------
extern "C" void kernel_launch(void* const* d_in, const int* in_sizes, int n_in,
                              void* d_out, int out_size, void* d_ws, size_t ws_size,
                              hipStream_t stream)
{
  const float* x    = (const float*)d_in[0];
  const float* fcos = (const float*)d_in[1];
  const float* fsin = (const float*)d_in[2];
  const float* wq   = (const float*)d_in[3];
  const float* wk   = (const float*)d_in[4];
  const float* wv   = (const float*)d_in[5];
  const float* wo   = (const float*)d_in[6];
  float* out = (float*)d_out;

  char* p = (char*)d_ws;
  short* xb  = (short*)p; p += (size_t)SEQ * DM * 2;
  short* wqb = (short*)p; p += (size_t)DM * DM * 2;    // wqb..wvb contiguous = W[6144][4096]
  short* wkb = (short*)p; p += (size_t)DKV * DM * 2;
  short* wvb = (short*)p; p += (size_t)DKV * DM * 2;
  short* wob = (short*)p; p += (size_t)DM * DM * 2;
  short* Qb  = (short*)p; p += (size_t)SEQ * DM * 2;
  short* Kb  = (short*)p; p += (size_t)SEQ * DKV * 2;
  short* Vt  = (short*)p; p += (size_t)DKV * SEQ * 2;
  short* Ab  = (short*)p; p += (size_t)SEQ * DM * 2;
  (void)wkb; (void)wvb;

  cvt_all_kernel<<<2048, 256, 0, stream>>>(x, wq, wk, wv, wo, xb);

  gemm8_kernel<1, 256, 192><<<dim3(32, 8), 512, 0, stream>>>(xb, wqb,
                                                             nullptr, Qb, Kb, Vt);
  rope_k_kernel<<<1024, 256, 0, stream>>>(Kb, fcos, fsin);
  flash_kernel<<<512, 256, 0, stream>>>(Qb, Kb, Vt, fcos, fsin, Ab);
  gemm8_kernel<0, 128, 256><<<dim3(16, 16), 512, 0, stream>>>(Ab, wob,
                                                              out, nullptr, nullptr, nullptr);
}